// Round 5
// baseline (1136.567 us; speedup 1.0000x reference)
//
#include <hip/hip_runtime.h>
#include <math.h>

#define S_ 2048
#define NH 8
#define DH 64
#define RSTRIDE 264   // padded row stride for R (r in [0,256] meaningful)

// ---------------------------------------------------------------------------
// Kernel 1: fused QKV GEMM.  x[4096,512] @ {Wq,Wk,Wv}[512,512] (fp32 vector).
// widx==0 writes qcon(+b_con, pre-scaled by 1/8) AND qrel(+b_rel); 1->k; 2->v.
// ---------------------------------------------------------------------------
__global__ __launch_bounds__(256) void qkv_gemm(
    const float* __restrict__ x,
    const float* __restrict__ Wq, const float* __restrict__ Wk, const float* __restrict__ Wv,
    const float* __restrict__ b_con, const float* __restrict__ b_rel, const float* __restrict__ bv,
    float* __restrict__ qcon, float* __restrict__ qrel,
    float* __restrict__ kout, float* __restrict__ vout)
{
    __shared__ float As[16][136];   // [k][m], padded
    __shared__ float Bs[16][128];   // [k][n]
    const int tid = threadIdx.x;
    const int tx = tid & 15, ty = tid >> 4;
    const int m0 = blockIdx.x * 128;
    const int gn0 = blockIdx.y * 128;
    const int widx = gn0 >> 9;
    const int col0 = gn0 & 511;
    const float* W = (widx == 0) ? Wq : (widx == 1) ? Wk : Wv;

    float acc[8][8] = {};

    const int arow = tid >> 1, akof = (tid & 1) * 8;
    const int brow = tid >> 4, bcof = (tid & 15) * 8;

    for (int k0 = 0; k0 < 512; k0 += 16) {
        float4 a0 = *(const float4*)&x[(size_t)(m0 + arow) * 512 + k0 + akof];
        float4 a1 = *(const float4*)&x[(size_t)(m0 + arow) * 512 + k0 + akof + 4];
        float4 b0 = *(const float4*)&W[(size_t)(k0 + brow) * 512 + col0 + bcof];
        float4 b1 = *(const float4*)&W[(size_t)(k0 + brow) * 512 + col0 + bcof + 4];
        As[akof + 0][arow] = a0.x; As[akof + 1][arow] = a0.y;
        As[akof + 2][arow] = a0.z; As[akof + 3][arow] = a0.w;
        As[akof + 4][arow] = a1.x; As[akof + 5][arow] = a1.y;
        As[akof + 6][arow] = a1.z; As[akof + 7][arow] = a1.w;
        *(float4*)&Bs[brow][bcof] = b0;
        *(float4*)&Bs[brow][bcof + 4] = b1;
        __syncthreads();
#pragma unroll
        for (int kk = 0; kk < 16; ++kk) {
            float a[8], bb[8];
            *(float4*)&a[0] = *(const float4*)&As[kk][ty * 8];
            *(float4*)&a[4] = *(const float4*)&As[kk][ty * 8 + 4];
            *(float4*)&bb[0] = *(const float4*)&Bs[kk][tx * 8];
            *(float4*)&bb[4] = *(const float4*)&Bs[kk][tx * 8 + 4];
#pragma unroll
            for (int i = 0; i < 8; ++i)
#pragma unroll
                for (int j = 0; j < 8; ++j) acc[i][j] += a[i] * bb[j];
        }
        __syncthreads();
    }

    const int col = col0 + tx * 8;
    if (widx == 0) {
        float bc[8], br[8];
        *(float4*)&bc[0] = *(const float4*)&b_con[col];
        *(float4*)&bc[4] = *(const float4*)&b_con[col + 4];
        *(float4*)&br[0] = *(const float4*)&b_rel[col];
        *(float4*)&br[4] = *(const float4*)&b_rel[col + 4];
#pragma unroll
        for (int i = 0; i < 8; ++i) {
            size_t base = (size_t)(m0 + ty * 8 + i) * 512 + col;
            float o1[8], o2[8];
#pragma unroll
            for (int j = 0; j < 8; ++j) {
                o1[j] = (acc[i][j] + bc[j]) * 0.125f;   // fold 1/sqrt(Dh)
                o2[j] = acc[i][j] + br[j];
            }
            *(float4*)&qcon[base]     = *(float4*)&o1[0];
            *(float4*)&qcon[base + 4] = *(float4*)&o1[4];
            *(float4*)&qrel[base]     = *(float4*)&o2[0];
            *(float4*)&qrel[base + 4] = *(float4*)&o2[4];
        }
    } else if (widx == 1) {
#pragma unroll
        for (int i = 0; i < 8; ++i) {
            size_t base = (size_t)(m0 + ty * 8 + i) * 512 + col;
            *(float4*)&kout[base]     = *(float4*)&acc[i][0];
            *(float4*)&kout[base + 4] = *(float4*)&acc[i][4];
        }
    } else {
        float bb[8];
        *(float4*)&bb[0] = *(const float4*)&bv[col];
        *(float4*)&bb[4] = *(const float4*)&bv[col + 4];
#pragma unroll
        for (int i = 0; i < 8; ++i) {
            size_t base = (size_t)(m0 + ty * 8 + i) * 512 + col;
            float o[8];
#pragma unroll
            for (int j = 0; j < 8; ++j) o[j] = acc[i][j] + bb[j];
            *(float4*)&vout[base]     = *(float4*)&o[0];
            *(float4*)&vout[base + 4] = *(float4*)&o[4];
        }
    }
}

// ---------------------------------------------------------------------------
// Kernel 2: krel[r,e] = pos_emb_row(r) @ Wkr, r in [0,256].
// ---------------------------------------------------------------------------
__global__ __launch_bounds__(256) void krel_gemm(
    const float* __restrict__ Wkr, float* __restrict__ krel)
{
    __shared__ float As[16][68];
    __shared__ float Bs[16][64];
    const int tid = threadIdx.x;
    const int tx = tid & 15, ty = tid >> 4;
    const int m0 = blockIdx.x * 64;
    const int col0 = blockIdx.y * 64;
    float acc[4][4] = {};
    const int arow = tid >> 2, ak4 = (tid & 3) * 4;
    const int brow = tid >> 4, bc4 = (tid & 15) * 4;
    const float rpos = (float)(m0 + arow);
    const float C = -0.051905126482615036f;   // -log2(10000)/256

    for (int k0 = 0; k0 < 512; k0 += 16) {
#pragma unroll
        for (int c = 0; c < 4; ++c) {
            int kg = k0 + ak4 + c;
            int f = kg >> 1;
            float invf = exp2f(C * (float)f);
            float ang = rpos * invf;
            As[ak4 + c][arow] = (kg & 1) ? cosf(ang) : sinf(ang);
        }
        *(float4*)&Bs[brow][bc4] =
            *(const float4*)&Wkr[(size_t)(k0 + brow) * 512 + col0 + bc4];
        __syncthreads();
#pragma unroll
        for (int kk = 0; kk < 16; ++kk) {
            float a[4], bb[4];
            *(float4*)&a[0]  = *(const float4*)&As[kk][ty * 4];
            *(float4*)&bb[0] = *(const float4*)&Bs[kk][tx * 4];
#pragma unroll
            for (int i = 0; i < 4; ++i)
#pragma unroll
                for (int j = 0; j < 4; ++j) acc[i][j] += a[i] * bb[j];
        }
        __syncthreads();
    }
#pragma unroll
    for (int i = 0; i < 4; ++i) {
        int r = m0 + ty * 4 + i;
        if (r <= 256) {
            float4 o = {acc[i][0], acc[i][1], acc[i][2], acc[i][3]};
            *(float4*)&krel[(size_t)r * 512 + col0 + tx * 4] = o;
        }
    }
}

// ---------------------------------------------------------------------------
// Kernel 3: R[b,n,i,r] = (qrel[b,i,n,:] . krel[r,n,:]) / 8   (r in [0,256])
// ---------------------------------------------------------------------------
__global__ __launch_bounds__(256) void rel_gemm(
    const float* __restrict__ qrel, const float* __restrict__ krel,
    float* __restrict__ R)
{
    const int tile = blockIdx.x, n = blockIdx.y, b = blockIdx.z;
    const int i0 = tile * 64;
    const int tid = threadIdx.x, lane = tid & 63, w = tid >> 6;
    __shared__ float q_lds[64][64];    // broadcast reads
    __shared__ float kr_lds[64][68];
    const int srow = tid >> 2, sc0 = (tid & 3) * 4;
#pragma unroll
    for (int c = 0; c < 4; ++c) {
        int d = sc0 + c * 16;
        *(float4*)&q_lds[srow][d] =
            *(const float4*)&qrel[((size_t)b * S_ + i0 + srow) * 512 + n * 64 + d];
    }
    const size_t rbase = ((size_t)(b * NH + n) * S_ + i0) * RSTRIDE;
    for (int rc = 0; rc < 5; ++rc) {
#pragma unroll
        for (int c = 0; c < 4; ++c) {
            int d = sc0 + c * 16;
            int rr = rc * 64 + srow;
            float4 kv = make_float4(0.f, 0.f, 0.f, 0.f);
            if (rr <= 256) kv = *(const float4*)&krel[(size_t)rr * 512 + n * 64 + d];
            *(float4*)&kr_lds[srow][d] = kv;
        }
        __syncthreads();
#pragma unroll 1
        for (int pg = 0; pg < 4; ++pg) {
            float dot[4] = {0.f, 0.f, 0.f, 0.f};
#pragma unroll
            for (int d4 = 0; d4 < 16; ++d4) {
                float4 k4 = *(const float4*)&kr_lds[lane][d4 * 4];
#pragma unroll
                for (int rr2 = 0; rr2 < 4; ++rr2) {
                    float4 q4 = *(const float4*)&q_lds[w * 16 + pg * 4 + rr2][d4 * 4];
                    dot[rr2] += q4.x * k4.x + q4.y * k4.y + q4.z * k4.z + q4.w * k4.w;
                }
            }
            int rg = rc * 64 + lane;
            if (rg < RSTRIDE) {
#pragma unroll
                for (int rr2 = 0; rr2 < 4; ++rr2)
                    R[rbase + (size_t)(w * 16 + pg * 4 + rr2) * RSTRIDE + rg]
                        = dot[rr2] * 0.125f;           // fold 1/sqrt(Dh)
            }
        }
        __syncthreads();
    }
}

// ---------------------------------------------------------------------------
// Kernel 4: vmean[b,e] = (1/S) sum_s v[b,s,e]
// ---------------------------------------------------------------------------
__global__ __launch_bounds__(512) void vmean_kernel(
    const float* __restrict__ v, float* __restrict__ vmean)
{
    const int b = blockIdx.x, sc = blockIdx.y;
    const int e = threadIdx.x;
    float sum = 0.f;
    for (int s = sc * 64; s < sc * 64 + 64; ++s)
        sum += v[((size_t)b * S_ + s) * 512 + e];
    atomicAdd(&vmean[(size_t)b * 512 + e], sum * (1.0f / (float)S_));
}

// ---------------------------------------------------------------------------
// Kernel 5: banded attention, batched softmax WITHOUT max subtraction.
// Round-5 changes vs round-4 (which ran 185us at VALUBusy 13%, VGPR=256,
// WRITE_SIZE 91MB = residual spill, 2 blocks/CU):
//  (a) p overlays k_lds (extra barrier) -> LDS 52.2KB -> 3 blocks/CU.
//  (b) R values prefetched into rv[16] at chunk top, issued alongside the
//      k/v staging loads (~800cyc of latency hiding) so the compiler has no
//      reason to hoist them itself with giant live ranges.
//  (c) __launch_bounds__(256,3) -> 168-VGPR cap.  Hand-counted peak live set
//      ~110 (acc16+pt16+rv16+q4/k4 32+addr), so the cap does NOT spill
//      (rounds 2/3 spilled because the cap sat far below the live set).
// Layout: 256 thr = 16(ty: 4-row groups) x 16(tx).  QK keys striped
// j = jc0+jj*16+tx (2-way banks, free).  PV: d = tx*4.  p via LDS transpose.
// Fully-masked rows (i >= xlen+256): all e=0 -> overridden by vmean.
// ---------------------------------------------------------------------------
__global__ __launch_bounds__(256, 3) void attn_kernel(
    const float* __restrict__ qcon, const float* __restrict__ kbuf,
    const float* __restrict__ vbuf, const float* __restrict__ R,
    const float* __restrict__ vmean, const int* __restrict__ xlen_p,
    float* __restrict__ out)
{
    const int tile = blockIdx.x, n = blockIdx.y, b = blockIdx.z;
    const int i0 = tile * 64;
    const int tid = threadIdx.x;
    const int tx = tid & 15;     // key-stripe (QK) / d-group (PV)
    const int ty = tid >> 4;     // row-group
    const int xlen = xlen_p[b];

    __shared__ float q_lds[64][68];
    __shared__ float kp_lds[64][68];   // k during QK, p during PV
    __shared__ float v_lds[64][68];

    const int srow = tid >> 2, sc0 = (tid & 3) * 16;

    // stage q tile (rows i0..i0+63); visible after the first in-loop barrier
    {
        const float* src = &qcon[((size_t)b * S_ + i0 + srow) * 512 + n * 64 + sc0];
#pragma unroll
        for (int cc = 0; cc < 4; ++cc)
            *(float4*)&q_lds[srow][sc0 + cc * 4] = *(const float4*)(src + cc * 4);
    }

    float acc[4][4] = {};
    float lpart[4] = {};
    // R row base for this thread's 4 rows; r(rr,jj) = rbase_r + rr - jj*16
    const size_t rrow0 = ((size_t)(b * NH + n) * S_ + i0) * RSTRIDE
                       + (size_t)(ty * 4) * RSTRIDE;

#pragma unroll 1
    for (int c = 0; c < 5; ++c) {
        const int jc0 = i0 - 256 + c * 64;
        const int rb = 256 - c * 64 + ty * 4 - tx;   // r at (rr=0,jj=0)
        __syncthreads();   // prev-iter PV reads of kp_lds/v_lds done

        // ---- prefetch R chunk values into registers (latency hidden) ----
        float rv[4][4];
#pragma unroll
        for (int rr = 0; rr < 4; ++rr) {
#pragma unroll
            for (int jj = 0; jj < 4; ++jj) {
                const int r = rb + rr - jj * 16;
                const int j = jc0 + jj * 16 + tx;
                const bool valid = (j >= 0) && (j < xlen) && (r >= 0) && (r <= 256);
                rv[rr][jj] = valid ? R[rrow0 + (size_t)rr * RSTRIDE + r] : 0.f;
            }
        }

        // ---- stage k and v chunks ----
        {
            const int jgs = jc0 + srow;
            const bool ok = (jgs >= 0);
            const float* ks = &kbuf[((size_t)b * S_ + jgs) * 512 + n * 64 + sc0];
            const float* vs = &vbuf[((size_t)b * S_ + jgs) * 512 + n * 64 + sc0];
            float4 z = make_float4(0.f, 0.f, 0.f, 0.f);
#pragma unroll
            for (int cc = 0; cc < 4; ++cc) {
                *(float4*)&kp_lds[srow][sc0 + cc * 4] = ok ? *(const float4*)(ks + cc * 4) : z;
                *(float4*)&v_lds[srow][sc0 + cc * 4]  = ok ? *(const float4*)(vs + cc * 4) : z;
            }
        }
        __syncthreads();

        // ---- QK 4x4 outer product over d (keys striped by 16) ----
        float pt[4][4] = {};
#pragma unroll
        for (int d4 = 0; d4 < 16; ++d4) {
            float4 q4[4], k4[4];
#pragma unroll
            for (int rr = 0; rr < 4; ++rr) q4[rr] = *(const float4*)&q_lds[ty * 4 + rr][d4 * 4];
#pragma unroll
            for (int jj = 0; jj < 4; ++jj) k4[jj] = *(const float4*)&kp_lds[jj * 16 + tx][d4 * 4];
#pragma unroll
            for (int rr = 0; rr < 4; ++rr)
#pragma unroll
                for (int jj = 0; jj < 4; ++jj)
                    pt[rr][jj] += q4[rr].x * k4[jj].x + q4[rr].y * k4[jj].y
                                + q4[rr].z * k4[jj].z + q4[rr].w * k4[jj].w;
        }

        // ---- mask + rel bias + exp (registers only) ----
#pragma unroll
        for (int rr = 0; rr < 4; ++rr) {
#pragma unroll
            for (int jj = 0; jj < 4; ++jj) {
                const int j = jc0 + jj * 16 + tx;
                const int r = rb + rr - jj * 16;
                const bool valid = (j >= 0) && (j < xlen) && (r >= 0) && (r <= 256);
                float e = valid ? __expf(pt[rr][jj] + rv[rr][jj]) : 0.f;
                pt[rr][jj] = e;
                lpart[rr] += e;
            }
        }
        __syncthreads();   // all waves' QK reads of kp_lds done

        // ---- overwrite kp_lds with p ----
#pragma unroll
        for (int rr = 0; rr < 4; ++rr)
#pragma unroll
            for (int jj = 0; jj < 4; ++jj)
                kp_lds[ty * 4 + rr][jj * 16 + tx] = pt[rr][jj];
        __syncthreads();

        // ---- PV 4x4 outer product over j ----
#pragma unroll
        for (int j4 = 0; j4 < 16; ++j4) {
            float4 p4[4], v4[4];
#pragma unroll
            for (int rr = 0; rr < 4; ++rr) p4[rr] = *(const float4*)&kp_lds[ty * 4 + rr][j4 * 4];
#pragma unroll
            for (int jj = 0; jj < 4; ++jj) v4[jj] = *(const float4*)&v_lds[j4 * 4 + jj][tx * 4];
#pragma unroll
            for (int rr = 0; rr < 4; ++rr) {
                acc[rr][0] += p4[rr].x * v4[0].x + p4[rr].y * v4[1].x
                            + p4[rr].z * v4[2].x + p4[rr].w * v4[3].x;
                acc[rr][1] += p4[rr].x * v4[0].y + p4[rr].y * v4[1].y
                            + p4[rr].z * v4[2].y + p4[rr].w * v4[3].y;
                acc[rr][2] += p4[rr].x * v4[0].z + p4[rr].y * v4[1].z
                            + p4[rr].z * v4[2].z + p4[rr].w * v4[3].z;
                acc[rr][3] += p4[rr].x * v4[0].w + p4[rr].y * v4[1].w
                            + p4[rr].z * v4[2].w + p4[rr].w * v4[3].w;
            }
        }
    }

    // ---- row sums across the 16 tx threads (lanes (ty%4)*16 + tx) ----
#pragma unroll
    for (int rr = 0; rr < 4; ++rr) {
#pragma unroll
        for (int off = 8; off >= 1; off >>= 1)
            lpart[rr] += __shfl_xor(lpart[rr], off, 64);
    }

    // ---- epilogue ----
#pragma unroll
    for (int rr = 0; rr < 4; ++rr) {
        const int i = i0 + ty * 4 + rr;
        float4 o;
        if (i >= xlen + 256) {
            o = *(const float4*)&vmean[(size_t)b * 512 + n * 64 + tx * 4];
        } else {
            float linv = 1.0f / lpart[rr];
            o = make_float4(acc[rr][0] * linv, acc[rr][1] * linv,
                            acc[rr][2] * linv, acc[rr][3] * linv);
        }
        *(float4*)&out[((size_t)b * S_ + i) * 512 + n * 64 + tx * 4] = o;
    }
}

// ---------------------------------------------------------------------------
extern "C" void kernel_launch(void* const* d_in, const int* in_sizes, int n_in,
                              void* d_out, int out_size, void* d_ws, size_t ws_size,
                              hipStream_t stream) {
    const float* x     = (const float*)d_in[0];
    const float* Wq    = (const float*)d_in[1];
    const float* b_con = (const float*)d_in[2];
    const float* b_rel = (const float*)d_in[3];
    const float* Wk    = (const float*)d_in[4];
    const float* Wkr   = (const float*)d_in[5];
    const float* Wv    = (const float*)d_in[6];
    const float* bv    = (const float*)d_in[7];
    const int*   xlen  = (const int*)d_in[8];
    float* out = (float*)d_out;

    float* ws = (float*)d_ws;
    float* qcon  = ws;                     // 4096*512
    float* qrel  = qcon  + 2097152;        // 4096*512
    float* kbuf  = qrel  + 2097152;        // 4096*512
    float* vbuf  = kbuf  + 2097152;        // 4096*512
    float* krel  = vbuf  + 2097152;        // 257*512 (rounded region)
    float* vmean = krel  + 131584;         // 2*512
    float* R     = vmean + 1024;           // 2*8*2048*264

    hipMemsetAsync(vmean, 0, 1024 * sizeof(float), stream);

    qkv_gemm<<<dim3(32, 12), 256, 0, stream>>>(x, Wq, Wk, Wv, b_con, b_rel, bv,
                                               qcon, qrel, kbuf, vbuf);
    krel_gemm<<<dim3(5, 8), 256, 0, stream>>>(Wkr, krel);
    rel_gemm<<<dim3(32, 8, 2), 256, 0, stream>>>(qrel, krel, R);
    vmean_kernel<<<dim3(2, 32), 512, 0, stream>>>(vbuf, vmean);
    attn_kernel<<<dim3(32, 8, 2), 256, 0, stream>>>(qcon, kbuf, vbuf, R, vmean,
                                                    xlen, out);
}

// Round 6
// 303.710 us; speedup vs baseline: 3.7423x; 3.7423x over previous
//
#include <hip/hip_runtime.h>
#include <math.h>

#define S_ 2048
#define NH 8
#define DH 64
#define RSTRIDE 264   // padded row stride for R (r in [0,256] meaningful)
#define LP 72         // bf16 LDS row pitch: 144 B = 9*16 B -> b128-aligned, conflict-free

typedef __attribute__((ext_vector_type(8))) short short8;   // 8 x bf16 (4 VGPRs)
typedef __attribute__((ext_vector_type(4))) float f32x4;    // MFMA accumulator

__device__ __forceinline__ short bf16r(float x) {   // RNE float->bf16
    union { float f; unsigned u; } v; v.f = x;
    unsigned r = v.u + 0x7fffu + ((v.u >> 16) & 1u);
    return (short)(r >> 16);
}

// ---------------------------------------------------------------------------
// Kernel 1: fused QKV GEMM.  x[4096,512] @ {Wq,Wk,Wv}[512,512] (fp32 vector).
// widx==0 writes qcon(+b_con, pre-scaled by 1/8) AND qrel(+b_rel); 1->k; 2->v.
// ---------------------------------------------------------------------------
__global__ __launch_bounds__(256) void qkv_gemm(
    const float* __restrict__ x,
    const float* __restrict__ Wq, const float* __restrict__ Wk, const float* __restrict__ Wv,
    const float* __restrict__ b_con, const float* __restrict__ b_rel, const float* __restrict__ bv,
    float* __restrict__ qcon, float* __restrict__ qrel,
    float* __restrict__ kout, float* __restrict__ vout)
{
    __shared__ float As[16][136];   // [k][m], padded
    __shared__ float Bs[16][128];   // [k][n]
    const int tid = threadIdx.x;
    const int tx = tid & 15, ty = tid >> 4;
    const int m0 = blockIdx.x * 128;
    const int gn0 = blockIdx.y * 128;
    const int widx = gn0 >> 9;
    const int col0 = gn0 & 511;
    const float* W = (widx == 0) ? Wq : (widx == 1) ? Wk : Wv;

    float acc[8][8] = {};

    const int arow = tid >> 1, akof = (tid & 1) * 8;
    const int brow = tid >> 4, bcof = (tid & 15) * 8;

    for (int k0 = 0; k0 < 512; k0 += 16) {
        float4 a0 = *(const float4*)&x[(size_t)(m0 + arow) * 512 + k0 + akof];
        float4 a1 = *(const float4*)&x[(size_t)(m0 + arow) * 512 + k0 + akof + 4];
        float4 b0 = *(const float4*)&W[(size_t)(k0 + brow) * 512 + col0 + bcof];
        float4 b1 = *(const float4*)&W[(size_t)(k0 + brow) * 512 + col0 + bcof + 4];
        As[akof + 0][arow] = a0.x; As[akof + 1][arow] = a0.y;
        As[akof + 2][arow] = a0.z; As[akof + 3][arow] = a0.w;
        As[akof + 4][arow] = a1.x; As[akof + 5][arow] = a1.y;
        As[akof + 6][arow] = a1.z; As[akof + 7][arow] = a1.w;
        *(float4*)&Bs[brow][bcof] = b0;
        *(float4*)&Bs[brow][bcof + 4] = b1;
        __syncthreads();
#pragma unroll
        for (int kk = 0; kk < 16; ++kk) {
            float a[8], bb[8];
            *(float4*)&a[0] = *(const float4*)&As[kk][ty * 8];
            *(float4*)&a[4] = *(const float4*)&As[kk][ty * 8 + 4];
            *(float4*)&bb[0] = *(const float4*)&Bs[kk][tx * 8];
            *(float4*)&bb[4] = *(const float4*)&Bs[kk][tx * 8 + 4];
#pragma unroll
            for (int i = 0; i < 8; ++i)
#pragma unroll
                for (int j = 0; j < 8; ++j) acc[i][j] += a[i] * bb[j];
        }
        __syncthreads();
    }

    const int col = col0 + tx * 8;
    if (widx == 0) {
        float bc[8], br[8];
        *(float4*)&bc[0] = *(const float4*)&b_con[col];
        *(float4*)&bc[4] = *(const float4*)&b_con[col + 4];
        *(float4*)&br[0] = *(const float4*)&b_rel[col];
        *(float4*)&br[4] = *(const float4*)&b_rel[col + 4];
#pragma unroll
        for (int i = 0; i < 8; ++i) {
            size_t base = (size_t)(m0 + ty * 8 + i) * 512 + col;
            float o1[8], o2[8];
#pragma unroll
            for (int j = 0; j < 8; ++j) {
                o1[j] = (acc[i][j] + bc[j]) * 0.125f;   // fold 1/sqrt(Dh)
                o2[j] = acc[i][j] + br[j];
            }
            *(float4*)&qcon[base]     = *(float4*)&o1[0];
            *(float4*)&qcon[base + 4] = *(float4*)&o1[4];
            *(float4*)&qrel[base]     = *(float4*)&o2[0];
            *(float4*)&qrel[base + 4] = *(float4*)&o2[4];
        }
    } else if (widx == 1) {
#pragma unroll
        for (int i = 0; i < 8; ++i) {
            size_t base = (size_t)(m0 + ty * 8 + i) * 512 + col;
            *(float4*)&kout[base]     = *(float4*)&acc[i][0];
            *(float4*)&kout[base + 4] = *(float4*)&acc[i][4];
        }
    } else {
        float bb[8];
        *(float4*)&bb[0] = *(const float4*)&bv[col];
        *(float4*)&bb[4] = *(const float4*)&bv[col + 4];
#pragma unroll
        for (int i = 0; i < 8; ++i) {
            size_t base = (size_t)(m0 + ty * 8 + i) * 512 + col;
            float o[8];
#pragma unroll
            for (int j = 0; j < 8; ++j) o[j] = acc[i][j] + bb[j];
            *(float4*)&vout[base]     = *(float4*)&o[0];
            *(float4*)&vout[base + 4] = *(float4*)&o[4];
        }
    }
}

// ---------------------------------------------------------------------------
// Kernel 2: krel[r,e] = pos_emb_row(r) @ Wkr, r in [0,256].
// ---------------------------------------------------------------------------
__global__ __launch_bounds__(256) void krel_gemm(
    const float* __restrict__ Wkr, float* __restrict__ krel)
{
    __shared__ float As[16][68];
    __shared__ float Bs[16][64];
    const int tid = threadIdx.x;
    const int tx = tid & 15, ty = tid >> 4;
    const int m0 = blockIdx.x * 64;
    const int col0 = blockIdx.y * 64;
    float acc[4][4] = {};
    const int arow = tid >> 2, ak4 = (tid & 3) * 4;
    const int brow = tid >> 4, bc4 = (tid & 15) * 4;
    const float rpos = (float)(m0 + arow);
    const float C = -0.051905126482615036f;   // -log2(10000)/256

    for (int k0 = 0; k0 < 512; k0 += 16) {
#pragma unroll
        for (int c = 0; c < 4; ++c) {
            int kg = k0 + ak4 + c;
            int f = kg >> 1;
            float invf = exp2f(C * (float)f);
            float ang = rpos * invf;
            As[ak4 + c][arow] = (kg & 1) ? cosf(ang) : sinf(ang);
        }
        *(float4*)&Bs[brow][bc4] =
            *(const float4*)&Wkr[(size_t)(k0 + brow) * 512 + col0 + bc4];
        __syncthreads();
#pragma unroll
        for (int kk = 0; kk < 16; ++kk) {
            float a[4], bb[4];
            *(float4*)&a[0]  = *(const float4*)&As[kk][ty * 4];
            *(float4*)&bb[0] = *(const float4*)&Bs[kk][tx * 4];
#pragma unroll
            for (int i = 0; i < 4; ++i)
#pragma unroll
                for (int j = 0; j < 4; ++j) acc[i][j] += a[i] * bb[j];
        }
        __syncthreads();
    }
#pragma unroll
    for (int i = 0; i < 4; ++i) {
        int r = m0 + ty * 4 + i;
        if (r <= 256) {
            float4 o = {acc[i][0], acc[i][1], acc[i][2], acc[i][3]};
            *(float4*)&krel[(size_t)r * 512 + col0 + tx * 4] = o;
        }
    }
}

// ---------------------------------------------------------------------------
// Kernel 3: R[b,n,i,r] = (qrel[b,i,n,:] . krel[r,n,:]) / 8   (r in [0,256])
// ---------------------------------------------------------------------------
__global__ __launch_bounds__(256) void rel_gemm(
    const float* __restrict__ qrel, const float* __restrict__ krel,
    float* __restrict__ R)
{
    const int tile = blockIdx.x, n = blockIdx.y, b = blockIdx.z;
    const int i0 = tile * 64;
    const int tid = threadIdx.x, lane = tid & 63, w = tid >> 6;
    __shared__ float q_lds[64][64];    // broadcast reads
    __shared__ float kr_lds[64][68];
    const int srow = tid >> 2, sc0 = (tid & 3) * 4;
#pragma unroll
    for (int c = 0; c < 4; ++c) {
        int d = sc0 + c * 16;
        *(float4*)&q_lds[srow][d] =
            *(const float4*)&qrel[((size_t)b * S_ + i0 + srow) * 512 + n * 64 + d];
    }
    const size_t rbase = ((size_t)(b * NH + n) * S_ + i0) * RSTRIDE;
    for (int rc = 0; rc < 5; ++rc) {
#pragma unroll
        for (int c = 0; c < 4; ++c) {
            int d = sc0 + c * 16;
            int rr = rc * 64 + srow;
            float4 kv = make_float4(0.f, 0.f, 0.f, 0.f);
            if (rr <= 256) kv = *(const float4*)&krel[(size_t)rr * 512 + n * 64 + d];
            *(float4*)&kr_lds[srow][d] = kv;
        }
        __syncthreads();
#pragma unroll 1
        for (int pg = 0; pg < 4; ++pg) {
            float dot[4] = {0.f, 0.f, 0.f, 0.f};
#pragma unroll
            for (int d4 = 0; d4 < 16; ++d4) {
                float4 k4 = *(const float4*)&kr_lds[lane][d4 * 4];
#pragma unroll
                for (int rr2 = 0; rr2 < 4; ++rr2) {
                    float4 q4 = *(const float4*)&q_lds[w * 16 + pg * 4 + rr2][d4 * 4];
                    dot[rr2] += q4.x * k4.x + q4.y * k4.y + q4.z * k4.z + q4.w * k4.w;
                }
            }
            int rg = rc * 64 + lane;
            if (rg < RSTRIDE) {
#pragma unroll
                for (int rr2 = 0; rr2 < 4; ++rr2)
                    R[rbase + (size_t)(w * 16 + pg * 4 + rr2) * RSTRIDE + rg]
                        = dot[rr2] * 0.125f;           // fold 1/sqrt(Dh)
            }
        }
        __syncthreads();
    }
}

// ---------------------------------------------------------------------------
// Kernel 4: vmean[b,e] = (1/S) sum_s v[b,s,e]
// ---------------------------------------------------------------------------
__global__ __launch_bounds__(512) void vmean_kernel(
    const float* __restrict__ v, float* __restrict__ vmean)
{
    const int b = blockIdx.x, sc = blockIdx.y;
    const int e = threadIdx.x;
    float sum = 0.f;
    for (int s = sc * 64; s < sc * 64 + 64; ++s)
        sum += v[((size_t)b * S_ + s) * 512 + e];
    atomicAdd(&vmean[(size_t)b * 512 + e], sum * (1.0f / (float)S_));
}

// ---------------------------------------------------------------------------
// Kernel 5: banded attention via bf16 MFMA (16x16x32), batched softmax
// without max subtraction (energies |s|<~3, exp overflow-safe, softmax
// shift-invariant -> matches reference).
// ROUND-6 REWRITE: rounds 2/3/5 proved the scalar-VALU 4x4 tile spills under
// ANY VGPR cap and burns 256 VGPR uncapped (R4: 185us, VALUBusy 13%).  MFMA
// moves the 4x4/lane tile into 4-reg accumulators -> live set ~100 VGPR,
// no cap needed, 2 barriers/chunk (separate p buffer).
// Block = (b, n, 64-q tile), 4 waves; wave w owns query rows w*16..w*16+15.
// Per 64-key chunk: QK = 4 jtiles x 2 ksteps MFMA; exp+mask+R on C-layout
// regs (fp32 lpart); p -> LDS bf16; PV = 4 ntiles x 2 ksteps MFMA.
// Layouts (m89/m120-verified): A[m=lane&15][k=quad*8+j]; C/D col=lane&15,
// row=quad*4+reg.  LDS bf16 pitch 72 (144 B = 9x16 B): b128 frag reads
// conflict-free.  Total LDS 36.9 KB.
// Fully-masked rows (i >= xlen+256): all e=0 -> overridden by vmean.
// ---------------------------------------------------------------------------
__global__ __launch_bounds__(256) void attn_kernel(
    const float* __restrict__ qcon, const float* __restrict__ kbuf,
    const float* __restrict__ vbuf, const float* __restrict__ R,
    const float* __restrict__ vmean, const int* __restrict__ xlen_p,
    float* __restrict__ out)
{
    const int tile = blockIdx.x, n = blockIdx.y, b = blockIdx.z;
    const int i0 = tile * 64;
    const int tid = threadIdx.x, lane = tid & 63, w = tid >> 6;
    const int quad = lane >> 4, l16 = lane & 15;
    const int xlen = xlen_p[b];

    __shared__ __align__(16) short q_lds[64][LP];
    __shared__ __align__(16) short k_lds[64][LP];
    __shared__ __align__(16) short vT_lds[64][LP];
    __shared__ __align__(16) short p_lds[64][LP];

    const int srow = tid >> 2, sc0 = (tid & 3) * 16;

    // ---- stage q tile as bf16 (rows i0..i0+63) ----
    {
        const float* src = &qcon[((size_t)b * S_ + i0 + srow) * 512 + n * 64 + sc0];
        short t16[16];
#pragma unroll
        for (int u = 0; u < 16; ++u) t16[u] = bf16r(src[u]);
        *(short8*)&q_lds[srow][sc0]     = *(short8*)&t16[0];
        *(short8*)&q_lds[srow][sc0 + 8] = *(short8*)&t16[8];
    }

    f32x4 Oa[4];
#pragma unroll
    for (int nt = 0; nt < 4; ++nt) Oa[nt] = (f32x4){0.f, 0.f, 0.f, 0.f};
    float lpart[4] = {};

    const size_t rrowB = (size_t)(b * NH + n) * S_ * RSTRIDE;

#pragma unroll 1
    for (int c = 0; c < 5; ++c) {
        const int jc0 = i0 - 256 + c * 64;
        __syncthreads();   // prev-chunk PV reads of p/vT done; q visible (c==0)

        // ---- prefetch R values for this thread's 16 score slots ----
        float rv[4][4];
#pragma unroll
        for (int jt = 0; jt < 4; ++jt) {
#pragma unroll
            for (int reg = 0; reg < 4; ++reg) {
                const int i = i0 + w * 16 + quad * 4 + reg;
                const int j = jc0 + jt * 16 + l16;
                const int r = i - j;
                const bool valid = (j >= 0) && (j < xlen) && (r >= 0) && (r <= 256);
                rv[jt][reg] = valid ? R[rrowB + (size_t)i * RSTRIDE + r] : 0.f;
            }
        }

        // ---- stage k chunk (bf16, row-major) and v chunk (bf16, transposed) ----
        {
            const int jg = jc0 + srow;
            const bool ok = (jg >= 0);
            const float* ks = &kbuf[((size_t)b * S_ + jg) * 512 + n * 64 + sc0];
            const float* vs = &vbuf[((size_t)b * S_ + jg) * 512 + n * 64 + sc0];
            short t16[16];
#pragma unroll
            for (int u = 0; u < 16; ++u) t16[u] = ok ? bf16r(ks[u]) : (short)0;
            *(short8*)&k_lds[srow][sc0]     = *(short8*)&t16[0];
            *(short8*)&k_lds[srow][sc0 + 8] = *(short8*)&t16[8];
#pragma unroll
            for (int u = 0; u < 16; ++u)
                vT_lds[sc0 + u][srow] = ok ? bf16r(vs[u]) : (short)0;
        }
        __syncthreads();

        // ---- QK: S[16 rows][64 j] via 4 jtiles x 2 ksteps MFMA ----
        short8 aq0 = *(const short8*)&q_lds[w * 16 + l16][quad * 8];
        short8 aq1 = *(const short8*)&q_lds[w * 16 + l16][quad * 8 + 32];
        f32x4 Sacc[4];
#pragma unroll
        for (int jt = 0; jt < 4; ++jt) {
            short8 bk0 = *(const short8*)&k_lds[jt * 16 + l16][quad * 8];
            short8 bk1 = *(const short8*)&k_lds[jt * 16 + l16][quad * 8 + 32];
            f32x4 s = (f32x4){0.f, 0.f, 0.f, 0.f};
            s = __builtin_amdgcn_mfma_f32_16x16x32_bf16(aq0, bk0, s, 0, 0, 0);
            s = __builtin_amdgcn_mfma_f32_16x16x32_bf16(aq1, bk1, s, 0, 0, 0);
            Sacc[jt] = s;
        }

        // ---- mask + rel bias + exp (fp32), p -> LDS bf16 ----
#pragma unroll
        for (int jt = 0; jt < 4; ++jt) {
#pragma unroll
            for (int reg = 0; reg < 4; ++reg) {
                const int i = i0 + w * 16 + quad * 4 + reg;
                const int j = jc0 + jt * 16 + l16;
                const int r = i - j;
                const bool valid = (j >= 0) && (j < xlen) && (r >= 0) && (r <= 256);
                float e = valid ? __expf(Sacc[jt][reg] + rv[jt][reg]) : 0.f;
                lpart[reg] += e;
                p_lds[w * 16 + quad * 4 + reg][jt * 16 + l16] = bf16r(e);
            }
        }
        __syncthreads();   // p complete for all waves; vT stable

        // ---- PV: O[16 rows][64 d] += P[16][64] V[64][64] ----
        short8 ap0 = *(const short8*)&p_lds[w * 16 + l16][quad * 8];
        short8 ap1 = *(const short8*)&p_lds[w * 16 + l16][quad * 8 + 32];
#pragma unroll
        for (int nt = 0; nt < 4; ++nt) {
            short8 bv0 = *(const short8*)&vT_lds[nt * 16 + l16][quad * 8];
            short8 bv1 = *(const short8*)&vT_lds[nt * 16 + l16][quad * 8 + 32];
            Oa[nt] = __builtin_amdgcn_mfma_f32_16x16x32_bf16(ap0, bv0, Oa[nt], 0, 0, 0);
            Oa[nt] = __builtin_amdgcn_mfma_f32_16x16x32_bf16(ap1, bv1, Oa[nt], 0, 0, 0);
        }
    }

    // ---- row sums: reduce lpart over the 16 lanes of each quad ----
#pragma unroll
    for (int reg = 0; reg < 4; ++reg) {
#pragma unroll
        for (int off = 1; off < 16; off <<= 1)
            lpart[reg] += __shfl_xor(lpart[reg], off, 64);
    }

    // ---- epilogue (C-layout: row = quad*4+reg, col = l16 within ntile) ----
#pragma unroll
    for (int reg = 0; reg < 4; ++reg) {
        const int i = i0 + w * 16 + quad * 4 + reg;
        const bool dead = (i >= xlen + 256);
        const float linv = 1.0f / lpart[reg];
#pragma unroll
        for (int nt = 0; nt < 4; ++nt) {
            const int d = n * 64 + nt * 16 + l16;
            float val = dead ? vmean[(size_t)b * 512 + d] : Oa[nt][reg] * linv;
            out[((size_t)b * S_ + i) * 512 + d] = val;
        }
    }
}

// ---------------------------------------------------------------------------
extern "C" void kernel_launch(void* const* d_in, const int* in_sizes, int n_in,
                              void* d_out, int out_size, void* d_ws, size_t ws_size,
                              hipStream_t stream) {
    const float* x     = (const float*)d_in[0];
    const float* Wq    = (const float*)d_in[1];
    const float* b_con = (const float*)d_in[2];
    const float* b_rel = (const float*)d_in[3];
    const float* Wk    = (const float*)d_in[4];
    const float* Wkr   = (const float*)d_in[5];
    const float* Wv    = (const float*)d_in[6];
    const float* bv    = (const float*)d_in[7];
    const int*   xlen  = (const int*)d_in[8];
    float* out = (float*)d_out;

    float* ws = (float*)d_ws;
    float* qcon  = ws;                     // 4096*512
    float* qrel  = qcon  + 2097152;        // 4096*512
    float* kbuf  = qrel  + 2097152;        // 4096*512
    float* vbuf  = kbuf  + 2097152;        // 4096*512
    float* krel  = vbuf  + 2097152;        // 257*512 (rounded region)
    float* vmean = krel  + 131584;         // 2*512
    float* R     = vmean + 1024;           // 2*8*2048*264

    hipMemsetAsync(vmean, 0, 1024 * sizeof(float), stream);

    qkv_gemm<<<dim3(32, 12), 256, 0, stream>>>(x, Wq, Wk, Wv, b_con, b_rel, bv,
                                               qcon, qrel, kbuf, vbuf);
    krel_gemm<<<dim3(5, 8), 256, 0, stream>>>(Wkr, krel);
    rel_gemm<<<dim3(32, 8, 2), 256, 0, stream>>>(qrel, krel, R);
    vmean_kernel<<<dim3(2, 32), 512, 0, stream>>>(vbuf, vmean);
    attn_kernel<<<dim3(32, 8, 2), 256, 0, stream>>>(qcon, kbuf, vbuf, R, vmean,
                                                    xlen, out);
}

// Round 7
// 206.838 us; speedup vs baseline: 5.4950x; 1.4684x over previous
//
#include <hip/hip_runtime.h>
#include <math.h>

#define S_ 2048
#define NH 8
#define DH 64
#define RSTRIDE 264   // padded row stride for R (r in [0,256] meaningful)
#define LP 72         // bf16 LDS row pitch (attn): 144 B = 9*16 B -> b128-aligned

typedef __attribute__((ext_vector_type(8))) short short8;   // 8 x bf16 (4 VGPRs)
typedef __attribute__((ext_vector_type(4))) float f32x4;    // MFMA accumulator
typedef unsigned short ushort_t;

__device__ __forceinline__ short bf16r(float x) {   // RNE float->bf16
    union { float f; unsigned u; } v; v.f = x;
    unsigned r = v.u + 0x7fffu + ((v.u >> 16) & 1u);
    return (short)(r >> 16);
}
__device__ __forceinline__ float b2f(ushort_t h) {  // bf16->float
    union { float f; unsigned u; } v; v.u = ((unsigned)h) << 16; return v.f;
}

// ---------------------------------------------------------------------------
// Kernel 0: WT[n][k] = bf16(W[k][n]) for Wq/Wk/Wv.  LDS-tiled 64x64,
// coalesced read and write.  Tiny (3 MB total).
// ---------------------------------------------------------------------------
__global__ __launch_bounds__(256) void wtrans_kernel(
    const float* __restrict__ Wq, const float* __restrict__ Wk, const float* __restrict__ Wv,
    ushort_t* __restrict__ WTq, ushort_t* __restrict__ WTk, ushort_t* __restrict__ WTv)
{
    const int widx = blockIdx.z;
    const float* W = (widx == 0) ? Wq : (widx == 1) ? Wk : Wv;
    ushort_t* WT   = (widx == 0) ? WTq : (widx == 1) ? WTk : WTv;
    const int k0 = blockIdx.x * 64, n0 = blockIdx.y * 64;
    __shared__ __align__(16) ushort_t T[64][72];
    const int t = threadIdx.x;
    const int srow = t >> 2, sc0 = (t & 3) * 16;
    const float* src = &W[(size_t)(k0 + srow) * 512 + n0 + sc0];
#pragma unroll
    for (int u = 0; u < 16; ++u) T[sc0 + u][srow] = (ushort_t)bf16r(src[u]);
    __syncthreads();
    ushort_t* dst = &WT[(size_t)(n0 + srow) * 512 + k0 + sc0];
    *(short8*)dst       = *(const short8*)&T[srow][sc0];
    *(short8*)(dst + 8) = *(const short8*)&T[srow][sc0 + 8];
}

// ---------------------------------------------------------------------------
// Kernel 1: fused QKV GEMM via bf16 MFMA.  out = x[4096,512] @ W[512,512].
// B-operand = WT rows (pre-transposed bf16) -> pure short8 staging, no
// in-kernel transpose (any b128-legal transposed-scatter pitch is 8-way
// bank-conflicted; that's why WT is precomputed).
// Block: 128(M) x 64(N), BK=32, 4 waves; wave w: rows w*32..+31 (2 mtiles),
// all 4 ntiles -> 8 acc f32x4, 6 b128 LDS reads per 8 MFMAs per kstep.
// Grid 32 x 24 = 768 blocks (3/CU; round-6's 384 was grid-starved).
// widx==0 writes qcon bf16 ((acc+b_con)*0.125) AND qrel fp32 (acc+b_rel);
// 1 -> k bf16; 2 -> v+bv bf16.  Consumers take bf16 (attn rounds anyway).
// ---------------------------------------------------------------------------
__global__ __launch_bounds__(256) void qkv_gemm(
    const float* __restrict__ x,
    const ushort_t* __restrict__ WTq, const ushort_t* __restrict__ WTk,
    const ushort_t* __restrict__ WTv,
    const float* __restrict__ b_con, const float* __restrict__ b_rel,
    const float* __restrict__ bv,
    ushort_t* __restrict__ qcon, float* __restrict__ qrel,
    ushort_t* __restrict__ kout, ushort_t* __restrict__ vout)
{
    const int m0 = blockIdx.x * 128;
    const int widx = blockIdx.y >> 3;
    const int n0 = (blockIdx.y & 7) * 64;
    const ushort_t* WT = (widx == 0) ? WTq : (widx == 1) ? WTk : WTv;
    const int tid = threadIdx.x, lane = tid & 63, w = tid >> 6;
    const int quad = lane >> 4, l16 = lane & 15;

    // pitch 40 shorts = 80 B: b128-aligned, 16-row frag reads are 2-way (free)
    __shared__ __align__(16) ushort_t A_lds[128][40];
    __shared__ __align__(16) ushort_t B_lds[64][40];

    f32x4 acc[2][4];
#pragma unroll
    for (int mt = 0; mt < 2; ++mt)
#pragma unroll
        for (int nt = 0; nt < 4; ++nt) acc[mt][nt] = (f32x4){0.f, 0.f, 0.f, 0.f};

    const int arow = tid >> 1, ak0 = (tid & 1) * 16;
    const int brow = tid >> 2, bk0 = (tid & 3) * 8;

    for (int k0 = 0; k0 < 512; k0 += 32) {
        // ---- stage A: x fp32 -> bf16 (64 B read, 2 short8 stores) ----
        const float* xs = &x[(size_t)(m0 + arow) * 512 + k0 + ak0];
        ushort_t t16[16];
#pragma unroll
        for (int u = 0; u < 16; ++u) t16[u] = (ushort_t)bf16r(xs[u]);
        *(short8*)&A_lds[arow][ak0]     = *(short8*)&t16[0];
        *(short8*)&A_lds[arow][ak0 + 8] = *(short8*)&t16[8];
        // ---- stage B: WT bf16 straight copy ----
        *(short8*)&B_lds[brow][bk0] =
            *(const short8*)&WT[(size_t)(n0 + brow) * 512 + k0 + bk0];
        __syncthreads();

        short8 a0 = *(const short8*)&A_lds[w * 32 + l16][quad * 8];
        short8 a1 = *(const short8*)&A_lds[w * 32 + 16 + l16][quad * 8];
#pragma unroll
        for (int nt = 0; nt < 4; ++nt) {
            short8 bb = *(const short8*)&B_lds[nt * 16 + l16][quad * 8];
            acc[0][nt] = __builtin_amdgcn_mfma_f32_16x16x32_bf16(a0, bb, acc[0][nt], 0, 0, 0);
            acc[1][nt] = __builtin_amdgcn_mfma_f32_16x16x32_bf16(a1, bb, acc[1][nt], 0, 0, 0);
        }
        __syncthreads();
    }

    // ---- epilogue (C layout: row = quad*4+reg, col = l16) ----
#pragma unroll
    for (int nt = 0; nt < 4; ++nt) {
        const int col = n0 + nt * 16 + l16;          // 0..511 within this W
        float bc = 0.f, br = 0.f;
        if (widx == 0) { bc = b_con[col]; br = b_rel[col]; }
        else if (widx == 2) { bc = bv[col]; }
#pragma unroll
        for (int mt = 0; mt < 2; ++mt) {
#pragma unroll
            for (int reg = 0; reg < 4; ++reg) {
                const size_t m = (size_t)(m0 + w * 32 + mt * 16 + quad * 4 + reg);
                const float val = acc[mt][nt][reg];
                if (widx == 0) {
                    qcon[m * 512 + col] = (ushort_t)bf16r((val + bc) * 0.125f);
                    qrel[m * 512 + col] = val + br;
                } else if (widx == 1) {
                    kout[m * 512 + col] = (ushort_t)bf16r(val);
                } else {
                    vout[m * 512 + col] = (ushort_t)bf16r(val + bc);
                }
            }
        }
    }
}

// ---------------------------------------------------------------------------
// Kernel 2: krel[r,e] = pos_emb_row(r) @ Wkr, r in [0,256].
// ---------------------------------------------------------------------------
__global__ __launch_bounds__(256) void krel_gemm(
    const float* __restrict__ Wkr, float* __restrict__ krel)
{
    __shared__ float As[16][68];
    __shared__ float Bs[16][64];
    const int tid = threadIdx.x;
    const int tx = tid & 15, ty = tid >> 4;
    const int m0 = blockIdx.x * 64;
    const int col0 = blockIdx.y * 64;
    float acc[4][4] = {};
    const int arow = tid >> 2, ak4 = (tid & 3) * 4;
    const int brow = tid >> 4, bc4 = (tid & 15) * 4;
    const float rpos = (float)(m0 + arow);
    const float C = -0.051905126482615036f;   // -log2(10000)/256

    for (int k0 = 0; k0 < 512; k0 += 16) {
#pragma unroll
        for (int c = 0; c < 4; ++c) {
            int kg = k0 + ak4 + c;
            int f = kg >> 1;
            float invf = exp2f(C * (float)f);
            float ang = rpos * invf;
            As[ak4 + c][arow] = (kg & 1) ? cosf(ang) : sinf(ang);
        }
        *(float4*)&Bs[brow][bc4] =
            *(const float4*)&Wkr[(size_t)(k0 + brow) * 512 + col0 + bc4];
        __syncthreads();
#pragma unroll
        for (int kk = 0; kk < 16; ++kk) {
            float a[4], bb[4];
            *(float4*)&a[0]  = *(const float4*)&As[kk][ty * 4];
            *(float4*)&bb[0] = *(const float4*)&Bs[kk][tx * 4];
#pragma unroll
            for (int i = 0; i < 4; ++i)
#pragma unroll
                for (int j = 0; j < 4; ++j) acc[i][j] += a[i] * bb[j];
        }
        __syncthreads();
    }
#pragma unroll
    for (int i = 0; i < 4; ++i) {
        int r = m0 + ty * 4 + i;
        if (r <= 256) {
            float4 o = {acc[i][0], acc[i][1], acc[i][2], acc[i][3]};
            *(float4*)&krel[(size_t)r * 512 + col0 + tx * 4] = o;
        }
    }
}

// ---------------------------------------------------------------------------
// Kernel 3: R[b,n,i,r] = (qrel[b,i,n,:] . krel[r,n,:]) / 8   (r in [0,256])
// ---------------------------------------------------------------------------
__global__ __launch_bounds__(256) void rel_gemm(
    const float* __restrict__ qrel, const float* __restrict__ krel,
    float* __restrict__ R)
{
    const int tile = blockIdx.x, n = blockIdx.y, b = blockIdx.z;
    const int i0 = tile * 64;
    const int tid = threadIdx.x, lane = tid & 63, w = tid >> 6;
    __shared__ float q_lds[64][64];    // broadcast reads
    __shared__ float kr_lds[64][68];
    const int srow = tid >> 2, sc0 = (tid & 3) * 4;
#pragma unroll
    for (int c = 0; c < 4; ++c) {
        int d = sc0 + c * 16;
        *(float4*)&q_lds[srow][d] =
            *(const float4*)&qrel[((size_t)b * S_ + i0 + srow) * 512 + n * 64 + d];
    }
    const size_t rbase = ((size_t)(b * NH + n) * S_ + i0) * RSTRIDE;
    for (int rc = 0; rc < 5; ++rc) {
#pragma unroll
        for (int c = 0; c < 4; ++c) {
            int d = sc0 + c * 16;
            int rr = rc * 64 + srow;
            float4 kv = make_float4(0.f, 0.f, 0.f, 0.f);
            if (rr <= 256) kv = *(const float4*)&krel[(size_t)rr * 512 + n * 64 + d];
            *(float4*)&kr_lds[srow][d] = kv;
        }
        __syncthreads();
#pragma unroll 1
        for (int pg = 0; pg < 4; ++pg) {
            float dot[4] = {0.f, 0.f, 0.f, 0.f};
#pragma unroll
            for (int d4 = 0; d4 < 16; ++d4) {
                float4 k4 = *(const float4*)&kr_lds[lane][d4 * 4];
#pragma unroll
                for (int rr2 = 0; rr2 < 4; ++rr2) {
                    float4 q4 = *(const float4*)&q_lds[w * 16 + pg * 4 + rr2][d4 * 4];
                    dot[rr2] += q4.x * k4.x + q4.y * k4.y + q4.z * k4.z + q4.w * k4.w;
                }
            }
            int rg = rc * 64 + lane;
            if (rg < RSTRIDE) {
#pragma unroll
                for (int rr2 = 0; rr2 < 4; ++rr2)
                    R[rbase + (size_t)(w * 16 + pg * 4 + rr2) * RSTRIDE + rg]
                        = dot[rr2] * 0.125f;           // fold 1/sqrt(Dh)
            }
        }
        __syncthreads();
    }
}

// ---------------------------------------------------------------------------
// Kernel 4: vmean[b,e] = (1/S) sum_s v[b,s,e]   (v now bf16)
// ---------------------------------------------------------------------------
__global__ __launch_bounds__(512) void vmean_kernel(
    const ushort_t* __restrict__ v, float* __restrict__ vmean)
{
    const int b = blockIdx.x, sc = blockIdx.y;
    const int e = threadIdx.x;
    float sum = 0.f;
    for (int s = sc * 64; s < sc * 64 + 64; ++s)
        sum += b2f(v[((size_t)b * S_ + s) * 512 + e]);
    atomicAdd(&vmean[(size_t)b * 512 + e], sum * (1.0f / (float)S_));
}

// ---------------------------------------------------------------------------
// Kernel 5: banded attention via bf16 MFMA (16x16x32), batched softmax
// without max subtraction.  Round-7 change: q/k/v arrive as bf16 from the
// MFMA QKV GEMM -> staging is pure short8 copies (round-6 burned 48 bf16r
// converts per thread per chunk here).
// ---------------------------------------------------------------------------
__global__ __launch_bounds__(256) void attn_kernel(
    const ushort_t* __restrict__ qcon, const ushort_t* __restrict__ kbuf,
    const ushort_t* __restrict__ vbuf, const float* __restrict__ R,
    const float* __restrict__ vmean, const int* __restrict__ xlen_p,
    float* __restrict__ out)
{
    const int tile = blockIdx.x, n = blockIdx.y, b = blockIdx.z;
    const int i0 = tile * 64;
    const int tid = threadIdx.x, lane = tid & 63, w = tid >> 6;
    const int quad = lane >> 4, l16 = lane & 15;
    const int xlen = xlen_p[b];

    __shared__ __align__(16) ushort_t q_lds[64][LP];
    __shared__ __align__(16) ushort_t k_lds[64][LP];
    __shared__ __align__(16) ushort_t vT_lds[64][LP];
    __shared__ __align__(16) ushort_t p_lds[64][LP];

    const int srow = tid >> 2, sc0 = (tid & 3) * 16;

    // ---- stage q tile (bf16 copy) ----
    {
        const ushort_t* src = &qcon[((size_t)b * S_ + i0 + srow) * 512 + n * 64 + sc0];
        *(short8*)&q_lds[srow][sc0]     = *(const short8*)src;
        *(short8*)&q_lds[srow][sc0 + 8] = *(const short8*)(src + 8);
    }

    f32x4 Oa[4];
#pragma unroll
    for (int nt = 0; nt < 4; ++nt) Oa[nt] = (f32x4){0.f, 0.f, 0.f, 0.f};
    float lpart[4] = {};

    const size_t rrowB = (size_t)(b * NH + n) * S_ * RSTRIDE;

#pragma unroll 1
    for (int c = 0; c < 5; ++c) {
        const int jc0 = i0 - 256 + c * 64;
        __syncthreads();   // prev-chunk PV reads of p/vT done; q visible (c==0)

        // ---- prefetch R values for this thread's 16 score slots ----
        float rv[4][4];
#pragma unroll
        for (int jt = 0; jt < 4; ++jt) {
#pragma unroll
            for (int reg = 0; reg < 4; ++reg) {
                const int i = i0 + w * 16 + quad * 4 + reg;
                const int j = jc0 + jt * 16 + l16;
                const int r = i - j;
                const bool valid = (j >= 0) && (j < xlen) && (r >= 0) && (r <= 256);
                rv[jt][reg] = valid ? R[rrowB + (size_t)i * RSTRIDE + r] : 0.f;
            }
        }

        // ---- stage k chunk (row-major) and v chunk (transposed), bf16 ----
        {
            const int jg = jc0 + srow;
            const bool ok = (jg >= 0);
            const ushort_t* ks = &kbuf[((size_t)b * S_ + jg) * 512 + n * 64 + sc0];
            const ushort_t* vs = &vbuf[((size_t)b * S_ + jg) * 512 + n * 64 + sc0];
            short8 z8 = {0, 0, 0, 0, 0, 0, 0, 0};
            *(short8*)&k_lds[srow][sc0]     = ok ? *(const short8*)ks : z8;
            *(short8*)&k_lds[srow][sc0 + 8] = ok ? *(const short8*)(ks + 8) : z8;
            ushort_t tv[16];
            *(short8*)&tv[0] = ok ? *(const short8*)vs : z8;
            *(short8*)&tv[8] = ok ? *(const short8*)(vs + 8) : z8;
#pragma unroll
            for (int u = 0; u < 16; ++u) vT_lds[sc0 + u][srow] = tv[u];
        }
        __syncthreads();

        // ---- QK: S[16 rows][64 j] via 4 jtiles x 2 ksteps MFMA ----
        short8 aq0 = *(const short8*)&q_lds[w * 16 + l16][quad * 8];
        short8 aq1 = *(const short8*)&q_lds[w * 16 + l16][quad * 8 + 32];
        f32x4 Sacc[4];
#pragma unroll
        for (int jt = 0; jt < 4; ++jt) {
            short8 bk0 = *(const short8*)&k_lds[jt * 16 + l16][quad * 8];
            short8 bk1 = *(const short8*)&k_lds[jt * 16 + l16][quad * 8 + 32];
            f32x4 s = (f32x4){0.f, 0.f, 0.f, 0.f};
            s = __builtin_amdgcn_mfma_f32_16x16x32_bf16(aq0, bk0, s, 0, 0, 0);
            s = __builtin_amdgcn_mfma_f32_16x16x32_bf16(aq1, bk1, s, 0, 0, 0);
            Sacc[jt] = s;
        }

        // ---- mask + rel bias + exp (fp32), p -> LDS bf16 ----
#pragma unroll
        for (int jt = 0; jt < 4; ++jt) {
#pragma unroll
            for (int reg = 0; reg < 4; ++reg) {
                const int i = i0 + w * 16 + quad * 4 + reg;
                const int j = jc0 + jt * 16 + l16;
                const int r = i - j;
                const bool valid = (j >= 0) && (j < xlen) && (r >= 0) && (r <= 256);
                float e = valid ? __expf(Sacc[jt][reg] + rv[jt][reg]) : 0.f;
                lpart[reg] += e;
                p_lds[w * 16 + quad * 4 + reg][jt * 16 + l16] = (ushort_t)bf16r(e);
            }
        }
        __syncthreads();   // p complete for all waves; vT stable

        // ---- PV: O[16 rows][64 d] += P[16][64] V[64][64] ----
        short8 ap0 = *(const short8*)&p_lds[w * 16 + l16][quad * 8];
        short8 ap1 = *(const short8*)&p_lds[w * 16 + l16][quad * 8 + 32];
#pragma unroll
        for (int nt = 0; nt < 4; ++nt) {
            short8 bv0 = *(const short8*)&vT_lds[nt * 16 + l16][quad * 8];
            short8 bv1 = *(const short8*)&vT_lds[nt * 16 + l16][quad * 8 + 32];
            Oa[nt] = __builtin_amdgcn_mfma_f32_16x16x32_bf16(ap0, bv0, Oa[nt], 0, 0, 0);
            Oa[nt] = __builtin_amdgcn_mfma_f32_16x16x32_bf16(ap1, bv1, Oa[nt], 0, 0, 0);
        }
    }

    // ---- row sums: reduce lpart over the 16 lanes of each quad ----
#pragma unroll
    for (int reg = 0; reg < 4; ++reg) {
#pragma unroll
        for (int off = 1; off < 16; off <<= 1)
            lpart[reg] += __shfl_xor(lpart[reg], off, 64);
    }

    // ---- epilogue (C-layout: row = quad*4+reg, col = l16 within ntile) ----
#pragma unroll
    for (int reg = 0; reg < 4; ++reg) {
        const int i = i0 + w * 16 + quad * 4 + reg;
        const bool dead = (i >= xlen + 256);
        const float linv = 1.0f / lpart[reg];
#pragma unroll
        for (int nt = 0; nt < 4; ++nt) {
            const int d = n * 64 + nt * 16 + l16;
            float val = dead ? vmean[(size_t)b * 512 + d] : Oa[nt][reg] * linv;
            out[((size_t)b * S_ + i) * 512 + d] = val;
        }
    }
}

// ---------------------------------------------------------------------------
extern "C" void kernel_launch(void* const* d_in, const int* in_sizes, int n_in,
                              void* d_out, int out_size, void* d_ws, size_t ws_size,
                              hipStream_t stream) {
    const float* x     = (const float*)d_in[0];
    const float* Wq    = (const float*)d_in[1];
    const float* b_con = (const float*)d_in[2];
    const float* b_rel = (const float*)d_in[3];
    const float* Wk    = (const float*)d_in[4];
    const float* Wkr   = (const float*)d_in[5];
    const float* Wv    = (const float*)d_in[6];
    const float* bv    = (const float*)d_in[7];
    const int*   xlen  = (const int*)d_in[8];
    float* out = (float*)d_out;

    float* ws = (float*)d_ws;
    float* qrel  = ws;                       // 4096*512 fp32
    float* krel  = qrel  + 2097152;          // 257*512 (rounded region)
    float* vmean = krel  + 131584;           // 2*512
    float* R     = vmean + 1024;             // 2*8*2048*264
    ushort_t* ub   = (ushort_t*)(R + 8650752);
    ushort_t* qcon = ub;                     // 4096*512 bf16
    ushort_t* kbuf = qcon + 2097152;
    ushort_t* vbuf = kbuf + 2097152;
    ushort_t* WTq  = vbuf + 2097152;         // 512*512 bf16 each
    ushort_t* WTk  = WTq + 262144;
    ushort_t* WTv  = WTk + 262144;

    hipMemsetAsync(vmean, 0, 1024 * sizeof(float), stream);

    wtrans_kernel<<<dim3(8, 8, 3), 256, 0, stream>>>(Wq, Wk, Wv, WTq, WTk, WTv);
    qkv_gemm<<<dim3(32, 24), 256, 0, stream>>>(x, WTq, WTk, WTv, b_con, b_rel, bv,
                                               qcon, qrel, kbuf, vbuf);
    krel_gemm<<<dim3(5, 8), 256, 0, stream>>>(Wkr, krel);
    rel_gemm<<<dim3(32, 8, 2), 256, 0, stream>>>(qrel, krel, R);
    vmean_kernel<<<dim3(2, 32), 512, 0, stream>>>(vbuf, vmean);
    attn_kernel<<<dim3(32, 8, 2), 256, 0, stream>>>(qcon, kbuf, vbuf, R, vmean,
                                                    xlen, out);
}

// Round 8
// 150.484 us; speedup vs baseline: 7.5528x; 1.3745x over previous
//
#include <hip/hip_runtime.h>
#include <math.h>

#define S_ 2048
#define NH 8
#define DH 64
#define RSTRIDE 264   // padded row stride for R (r in [0,256] meaningful)
#define LP 72         // bf16 LDS row pitch: 144 B = 9*16 B -> b128-aligned

typedef __attribute__((ext_vector_type(8))) short short8;   // 8 x bf16 (4 VGPRs)
typedef __attribute__((ext_vector_type(4))) float f32x4;    // MFMA accumulator
typedef unsigned short ushort_t;

__device__ __forceinline__ short bf16r(float x) {   // RNE float->bf16
    union { float f; unsigned u; } v; v.f = x;
    unsigned r = v.u + 0x7fffu + ((v.u >> 16) & 1u);
    return (short)(r >> 16);
}
__device__ __forceinline__ float b2f(ushort_t h) {  // bf16->float
    union { float f; unsigned u; } v; v.u = ((unsigned)h) << 16; return v.f;
}

// ---------------------------------------------------------------------------
// Kernel 0a: WT[n][k] = bf16(W[k][n]) for Wq/Wk/Wv/Wkr.  LDS-tiled 64x64.
// ---------------------------------------------------------------------------
__global__ __launch_bounds__(256) void wtrans_kernel(
    const float* __restrict__ Wq, const float* __restrict__ Wk,
    const float* __restrict__ Wv, const float* __restrict__ Wkr,
    ushort_t* __restrict__ WTq, ushort_t* __restrict__ WTk,
    ushort_t* __restrict__ WTv, ushort_t* __restrict__ WTkr)
{
    const int widx = blockIdx.z;
    const float* W = (widx == 0) ? Wq : (widx == 1) ? Wk : (widx == 2) ? Wv : Wkr;
    ushort_t* WT   = (widx == 0) ? WTq : (widx == 1) ? WTk : (widx == 2) ? WTv : WTkr;
    const int k0 = blockIdx.x * 64, n0 = blockIdx.y * 64;
    __shared__ __align__(16) ushort_t T[64][72];
    const int t = threadIdx.x;
    const int srow = t >> 2, sc0 = (t & 3) * 16;
    const float* src = &W[(size_t)(k0 + srow) * 512 + n0 + sc0];
#pragma unroll
    for (int u = 0; u < 16; ++u) T[sc0 + u][srow] = (ushort_t)bf16r(src[u]);
    __syncthreads();
    ushort_t* dst = &WT[(size_t)(n0 + srow) * 512 + k0 + sc0];
    *(short8*)dst       = *(const short8*)&T[srow][sc0];
    *(short8*)(dst + 8) = *(const short8*)&T[srow][sc0 + 8];
}

// ---------------------------------------------------------------------------
// Kernel 0b: pos[r][2f]=bf16(sin(r*invf)), [2f+1]=bf16(cos) for r in [0,256];
// rows 257..383 zero (MFMA tile padding).  Round-7's krel ran 49us because
// these transcendentals sat inside a 40-block GEMM (1 block/CU latency);
// here they're one sin+cos per thread across 384x256 threads.
// ---------------------------------------------------------------------------
__global__ __launch_bounds__(256) void pos_kernel(ushort_t* __restrict__ pos)
{
    const int r = blockIdx.x, f = threadIdx.x;
    const float C = -0.051905126482615036f;   // -log2(10000)/256
    unsigned pk = 0;
    if (r <= 256) {
        float ang = (float)r * exp2f(C * (float)f);
        unsigned s = (unsigned)(ushort_t)bf16r(sinf(ang));
        unsigned c = (unsigned)(ushort_t)bf16r(cosf(ang));
        pk = s | (c << 16);
    }
    ((unsigned*)pos)[(size_t)r * 256 + f] = pk;
}

// ---------------------------------------------------------------------------
// Kernel 1: fused QKV GEMM via bf16 MFMA.  out = x[4096,512] @ W[512,512].
// widx==0: qcon bf16 ((acc+b_con)*0.125) AND qrel bf16 ((acc+b_rel)*0.125);
// 1 -> k bf16; 2 -> v+bv bf16.
// ---------------------------------------------------------------------------
__global__ __launch_bounds__(256) void qkv_gemm(
    const float* __restrict__ x,
    const ushort_t* __restrict__ WTq, const ushort_t* __restrict__ WTk,
    const ushort_t* __restrict__ WTv,
    const float* __restrict__ b_con, const float* __restrict__ b_rel,
    const float* __restrict__ bv,
    ushort_t* __restrict__ qcon, ushort_t* __restrict__ qrel,
    ushort_t* __restrict__ kout, ushort_t* __restrict__ vout)
{
    const int m0 = blockIdx.x * 128;
    const int widx = blockIdx.y >> 3;
    const int n0 = (blockIdx.y & 7) * 64;
    const ushort_t* WT = (widx == 0) ? WTq : (widx == 1) ? WTk : WTv;
    const int tid = threadIdx.x, lane = tid & 63, w = tid >> 6;
    const int quad = lane >> 4, l16 = lane & 15;

    __shared__ __align__(16) ushort_t A_lds[128][40];
    __shared__ __align__(16) ushort_t B_lds[64][40];

    f32x4 acc[2][4];
#pragma unroll
    for (int mt = 0; mt < 2; ++mt)
#pragma unroll
        for (int nt = 0; nt < 4; ++nt) acc[mt][nt] = (f32x4){0.f, 0.f, 0.f, 0.f};

    const int arow = tid >> 1, ak0 = (tid & 1) * 16;
    const int brow = tid >> 2, bk0 = (tid & 3) * 8;

    for (int k0 = 0; k0 < 512; k0 += 32) {
        const float* xs = &x[(size_t)(m0 + arow) * 512 + k0 + ak0];
        ushort_t t16[16];
#pragma unroll
        for (int u = 0; u < 16; ++u) t16[u] = (ushort_t)bf16r(xs[u]);
        *(short8*)&A_lds[arow][ak0]     = *(short8*)&t16[0];
        *(short8*)&A_lds[arow][ak0 + 8] = *(short8*)&t16[8];
        *(short8*)&B_lds[brow][bk0] =
            *(const short8*)&WT[(size_t)(n0 + brow) * 512 + k0 + bk0];
        __syncthreads();

        short8 a0 = *(const short8*)&A_lds[w * 32 + l16][quad * 8];
        short8 a1 = *(const short8*)&A_lds[w * 32 + 16 + l16][quad * 8];
#pragma unroll
        for (int nt = 0; nt < 4; ++nt) {
            short8 bb = *(const short8*)&B_lds[nt * 16 + l16][quad * 8];
            acc[0][nt] = __builtin_amdgcn_mfma_f32_16x16x32_bf16(a0, bb, acc[0][nt], 0, 0, 0);
            acc[1][nt] = __builtin_amdgcn_mfma_f32_16x16x32_bf16(a1, bb, acc[1][nt], 0, 0, 0);
        }
        __syncthreads();
    }

#pragma unroll
    for (int nt = 0; nt < 4; ++nt) {
        const int col = n0 + nt * 16 + l16;
        float bc = 0.f, br = 0.f;
        if (widx == 0) { bc = b_con[col]; br = b_rel[col]; }
        else if (widx == 2) { bc = bv[col]; }
#pragma unroll
        for (int mt = 0; mt < 2; ++mt) {
#pragma unroll
            for (int reg = 0; reg < 4; ++reg) {
                const size_t m = (size_t)(m0 + w * 32 + mt * 16 + quad * 4 + reg);
                const float val = acc[mt][nt][reg];
                if (widx == 0) {
                    qcon[m * 512 + col] = (ushort_t)bf16r((val + bc) * 0.125f);
                    qrel[m * 512 + col] = (ushort_t)bf16r((val + br) * 0.125f);
                } else if (widx == 1) {
                    kout[m * 512 + col] = (ushort_t)bf16r(val);
                } else {
                    vout[m * 512 + col] = (ushort_t)bf16r(val + bc);
                }
            }
        }
    }
}

// ---------------------------------------------------------------------------
// Kernel 2: krel[r][e] bf16 = pos[r][:] @ Wkr (MFMA; M=384, N=512, K=512).
// Rows >256 are zero (pos rows zero).  Grid (3,8) = 24 blocks.
// ---------------------------------------------------------------------------
__global__ __launch_bounds__(256) void krel_gemm(
    const ushort_t* __restrict__ pos, const ushort_t* __restrict__ WTkr,
    ushort_t* __restrict__ krel)
{
    const int m0 = blockIdx.x * 128;
    const int n0 = blockIdx.y * 64;
    const int tid = threadIdx.x, lane = tid & 63, w = tid >> 6;
    const int quad = lane >> 4, l16 = lane & 15;

    __shared__ __align__(16) ushort_t A_lds[128][40];
    __shared__ __align__(16) ushort_t B_lds[64][40];

    f32x4 acc[2][4];
#pragma unroll
    for (int mt = 0; mt < 2; ++mt)
#pragma unroll
        for (int nt = 0; nt < 4; ++nt) acc[mt][nt] = (f32x4){0.f, 0.f, 0.f, 0.f};

    const int arow = tid >> 1, ak0 = (tid & 1) * 16;
    const int brow = tid >> 2, bk0 = (tid & 3) * 8;

    for (int k0 = 0; k0 < 512; k0 += 32) {
        const ushort_t* ps = &pos[(size_t)(m0 + arow) * 512 + k0 + ak0];
        *(short8*)&A_lds[arow][ak0]     = *(const short8*)ps;
        *(short8*)&A_lds[arow][ak0 + 8] = *(const short8*)(ps + 8);
        *(short8*)&B_lds[brow][bk0] =
            *(const short8*)&WTkr[(size_t)(n0 + brow) * 512 + k0 + bk0];
        __syncthreads();

        short8 a0 = *(const short8*)&A_lds[w * 32 + l16][quad * 8];
        short8 a1 = *(const short8*)&A_lds[w * 32 + 16 + l16][quad * 8];
#pragma unroll
        for (int nt = 0; nt < 4; ++nt) {
            short8 bb = *(const short8*)&B_lds[nt * 16 + l16][quad * 8];
            acc[0][nt] = __builtin_amdgcn_mfma_f32_16x16x32_bf16(a0, bb, acc[0][nt], 0, 0, 0);
            acc[1][nt] = __builtin_amdgcn_mfma_f32_16x16x32_bf16(a1, bb, acc[1][nt], 0, 0, 0);
        }
        __syncthreads();
    }

#pragma unroll
    for (int nt = 0; nt < 4; ++nt) {
        const int col = n0 + nt * 16 + l16;
#pragma unroll
        for (int mt = 0; mt < 2; ++mt)
#pragma unroll
            for (int reg = 0; reg < 4; ++reg) {
                const size_t m = (size_t)(m0 + w * 32 + mt * 16 + quad * 4 + reg);
                krel[m * 512 + col] = (ushort_t)bf16r(acc[mt][nt][reg]);
            }
    }
}

// ---------------------------------------------------------------------------
// Kernel 3: R[b,n,i,r] fp32 = qrel[b,i,n,:] . krel[r,n,:]  (scale already in
// qrel).  MFMA: block = (128-i tile, n, b); A staged once, B in 5 chunks of
// 64 r (rows 257..319 of krel are zero).  LDS 27.6 KB -> 5 blocks/CU.
// ---------------------------------------------------------------------------
__global__ __launch_bounds__(256) void rel_gemm(
    const ushort_t* __restrict__ qrel, const ushort_t* __restrict__ krel,
    float* __restrict__ R)
{
    const int tile = blockIdx.x, n = blockIdx.y, b = blockIdx.z;
    const int i0 = tile * 128;
    const int tid = threadIdx.x, lane = tid & 63, w = tid >> 6;
    const int quad = lane >> 4, l16 = lane & 15;

    __shared__ __align__(16) ushort_t A_lds[128][LP];
    __shared__ __align__(16) ushort_t B_lds[64][LP];

    // stage A: qrel rows i0..i0+127, d slice n*64..n*64+63
    {
        const int srow = tid >> 1, sc0 = (tid & 1) * 32;
        const ushort_t* src = &qrel[((size_t)b * S_ + i0 + srow) * 512 + n * 64 + sc0];
#pragma unroll
        for (int u = 0; u < 4; ++u)
            *(short8*)&A_lds[srow][sc0 + u * 8] = *(const short8*)(src + u * 8);
    }

    const size_t rbase = ((size_t)(b * NH + n) * S_ + i0) * RSTRIDE;
    const int srow2 = tid >> 2, sc2 = (tid & 3) * 16;

#pragma unroll 1
    for (int rc = 0; rc < 5; ++rc) {
        __syncthreads();   // A visible (rc==0) / prev chunk's B reads done
        {
            const ushort_t* src = &krel[(size_t)(rc * 64 + srow2) * 512 + n * 64 + sc2];
            *(short8*)&B_lds[srow2][sc2]     = *(const short8*)src;
            *(short8*)&B_lds[srow2][sc2 + 8] = *(const short8*)(src + 8);
        }
        __syncthreads();

        short8 a[2][2];
#pragma unroll
        for (int mt = 0; mt < 2; ++mt) {
            a[mt][0] = *(const short8*)&A_lds[w * 32 + mt * 16 + l16][quad * 8];
            a[mt][1] = *(const short8*)&A_lds[w * 32 + mt * 16 + l16][quad * 8 + 32];
        }
#pragma unroll
        for (int nt = 0; nt < 4; ++nt) {
            short8 b0 = *(const short8*)&B_lds[nt * 16 + l16][quad * 8];
            short8 b1 = *(const short8*)&B_lds[nt * 16 + l16][quad * 8 + 32];
            const int r = rc * 64 + nt * 16 + l16;
#pragma unroll
            for (int mt = 0; mt < 2; ++mt) {
                f32x4 s = (f32x4){0.f, 0.f, 0.f, 0.f};
                s = __builtin_amdgcn_mfma_f32_16x16x32_bf16(a[mt][0], b0, s, 0, 0, 0);
                s = __builtin_amdgcn_mfma_f32_16x16x32_bf16(a[mt][1], b1, s, 0, 0, 0);
                if (r < RSTRIDE) {
#pragma unroll
                    for (int reg = 0; reg < 4; ++reg) {
                        const int i = w * 32 + mt * 16 + quad * 4 + reg;
                        R[rbase + (size_t)i * RSTRIDE + r] = s[reg];
                    }
                }
            }
        }
    }
}

// ---------------------------------------------------------------------------
// Kernel 4: vmean[b,e] = (1/S) sum_s v[b,s,e]   (v bf16)
// ---------------------------------------------------------------------------
__global__ __launch_bounds__(512) void vmean_kernel(
    const ushort_t* __restrict__ v, float* __restrict__ vmean)
{
    const int b = blockIdx.x, sc = blockIdx.y;
    const int e = threadIdx.x;
    float sum = 0.f;
    for (int s = sc * 64; s < sc * 64 + 64; ++s)
        sum += b2f(v[((size_t)b * S_ + s) * 512 + e]);
    atomicAdd(&vmean[(size_t)b * 512 + e], sum * (1.0f / (float)S_));
}

// ---------------------------------------------------------------------------
// Kernel 5: banded attention via bf16 MFMA (16x16x32), batched softmax
// without max subtraction (energies |s|<~3; softmax shift-invariant).
// ---------------------------------------------------------------------------
__global__ __launch_bounds__(256) void attn_kernel(
    const ushort_t* __restrict__ qcon, const ushort_t* __restrict__ kbuf,
    const ushort_t* __restrict__ vbuf, const float* __restrict__ R,
    const float* __restrict__ vmean, const int* __restrict__ xlen_p,
    float* __restrict__ out)
{
    const int tile = blockIdx.x, n = blockIdx.y, b = blockIdx.z;
    const int i0 = tile * 64;
    const int tid = threadIdx.x, lane = tid & 63, w = tid >> 6;
    const int quad = lane >> 4, l16 = lane & 15;
    const int xlen = xlen_p[b];

    __shared__ __align__(16) ushort_t q_lds[64][LP];
    __shared__ __align__(16) ushort_t k_lds[64][LP];
    __shared__ __align__(16) ushort_t vT_lds[64][LP];
    __shared__ __align__(16) ushort_t p_lds[64][LP];

    const int srow = tid >> 2, sc0 = (tid & 3) * 16;

    {
        const ushort_t* src = &qcon[((size_t)b * S_ + i0 + srow) * 512 + n * 64 + sc0];
        *(short8*)&q_lds[srow][sc0]     = *(const short8*)src;
        *(short8*)&q_lds[srow][sc0 + 8] = *(const short8*)(src + 8);
    }

    f32x4 Oa[4];
#pragma unroll
    for (int nt = 0; nt < 4; ++nt) Oa[nt] = (f32x4){0.f, 0.f, 0.f, 0.f};
    float lpart[4] = {};

    const size_t rrowB = (size_t)(b * NH + n) * S_ * RSTRIDE;

#pragma unroll 1
    for (int c = 0; c < 5; ++c) {
        const int jc0 = i0 - 256 + c * 64;
        __syncthreads();

        float rv[4][4];
#pragma unroll
        for (int jt = 0; jt < 4; ++jt) {
#pragma unroll
            for (int reg = 0; reg < 4; ++reg) {
                const int i = i0 + w * 16 + quad * 4 + reg;
                const int j = jc0 + jt * 16 + l16;
                const int r = i - j;
                const bool valid = (j >= 0) && (j < xlen) && (r >= 0) && (r <= 256);
                rv[jt][reg] = valid ? R[rrowB + (size_t)i * RSTRIDE + r] : 0.f;
            }
        }

        {
            const int jg = jc0 + srow;
            const bool ok = (jg >= 0);
            const ushort_t* ks = &kbuf[((size_t)b * S_ + jg) * 512 + n * 64 + sc0];
            const ushort_t* vs = &vbuf[((size_t)b * S_ + jg) * 512 + n * 64 + sc0];
            short8 z8 = {0, 0, 0, 0, 0, 0, 0, 0};
            *(short8*)&k_lds[srow][sc0]     = ok ? *(const short8*)ks : z8;
            *(short8*)&k_lds[srow][sc0 + 8] = ok ? *(const short8*)(ks + 8) : z8;
            ushort_t tv[16];
            *(short8*)&tv[0] = ok ? *(const short8*)vs : z8;
            *(short8*)&tv[8] = ok ? *(const short8*)(vs + 8) : z8;
#pragma unroll
            for (int u = 0; u < 16; ++u) vT_lds[sc0 + u][srow] = tv[u];
        }
        __syncthreads();

        short8 aq0 = *(const short8*)&q_lds[w * 16 + l16][quad * 8];
        short8 aq1 = *(const short8*)&q_lds[w * 16 + l16][quad * 8 + 32];
        f32x4 Sacc[4];
#pragma unroll
        for (int jt = 0; jt < 4; ++jt) {
            short8 bk0 = *(const short8*)&k_lds[jt * 16 + l16][quad * 8];
            short8 bk1 = *(const short8*)&k_lds[jt * 16 + l16][quad * 8 + 32];
            f32x4 s = (f32x4){0.f, 0.f, 0.f, 0.f};
            s = __builtin_amdgcn_mfma_f32_16x16x32_bf16(aq0, bk0, s, 0, 0, 0);
            s = __builtin_amdgcn_mfma_f32_16x16x32_bf16(aq1, bk1, s, 0, 0, 0);
            Sacc[jt] = s;
        }

#pragma unroll
        for (int jt = 0; jt < 4; ++jt) {
#pragma unroll
            for (int reg = 0; reg < 4; ++reg) {
                const int i = i0 + w * 16 + quad * 4 + reg;
                const int j = jc0 + jt * 16 + l16;
                const int r = i - j;
                const bool valid = (j >= 0) && (j < xlen) && (r >= 0) && (r <= 256);
                float e = valid ? __expf(Sacc[jt][reg] + rv[jt][reg]) : 0.f;
                lpart[reg] += e;
                p_lds[w * 16 + quad * 4 + reg][jt * 16 + l16] = (ushort_t)bf16r(e);
            }
        }
        __syncthreads();

        short8 ap0 = *(const short8*)&p_lds[w * 16 + l16][quad * 8];
        short8 ap1 = *(const short8*)&p_lds[w * 16 + l16][quad * 8 + 32];
#pragma unroll
        for (int nt = 0; nt < 4; ++nt) {
            short8 bv0 = *(const short8*)&vT_lds[nt * 16 + l16][quad * 8];
            short8 bv1 = *(const short8*)&vT_lds[nt * 16 + l16][quad * 8 + 32];
            Oa[nt] = __builtin_amdgcn_mfma_f32_16x16x32_bf16(ap0, bv0, Oa[nt], 0, 0, 0);
            Oa[nt] = __builtin_amdgcn_mfma_f32_16x16x32_bf16(ap1, bv1, Oa[nt], 0, 0, 0);
        }
    }

#pragma unroll
    for (int reg = 0; reg < 4; ++reg) {
#pragma unroll
        for (int off = 1; off < 16; off <<= 1)
            lpart[reg] += __shfl_xor(lpart[reg], off, 64);
    }

#pragma unroll
    for (int reg = 0; reg < 4; ++reg) {
        const int i = i0 + w * 16 + quad * 4 + reg;
        const bool dead = (i >= xlen + 256);
        const float linv = 1.0f / lpart[reg];
#pragma unroll
        for (int nt = 0; nt < 4; ++nt) {
            const int d = n * 64 + nt * 16 + l16;
            float val = dead ? vmean[(size_t)b * 512 + d] : Oa[nt][reg] * linv;
            out[((size_t)b * S_ + i) * 512 + d] = val;
        }
    }
}

// ---------------------------------------------------------------------------
extern "C" void kernel_launch(void* const* d_in, const int* in_sizes, int n_in,
                              void* d_out, int out_size, void* d_ws, size_t ws_size,
                              hipStream_t stream) {
    const float* x     = (const float*)d_in[0];
    const float* Wq    = (const float*)d_in[1];
    const float* b_con = (const float*)d_in[2];
    const float* b_rel = (const float*)d_in[3];
    const float* Wk    = (const float*)d_in[4];
    const float* Wkr   = (const float*)d_in[5];
    const float* Wv    = (const float*)d_in[6];
    const float* bv    = (const float*)d_in[7];
    const int*   xlen  = (const int*)d_in[8];
    float* out = (float*)d_out;

    float* ws = (float*)d_ws;
    float* vmean = ws;                       // 1024 fp32
    float* R     = vmean + 1024;             // 2*8*2048*264 fp32
    ushort_t* ub   = (ushort_t*)(R + 8650752);
    ushort_t* qcon = ub;                     // 4096*512 bf16
    ushort_t* kbuf = qcon + 2097152;
    ushort_t* vbuf = kbuf + 2097152;
    ushort_t* qrel = vbuf + 2097152;         // 4096*512 bf16
    ushort_t* krel = qrel + 2097152;         // 384*512 bf16
    ushort_t* pos  = krel + 196608;          // 384*512 bf16
    ushort_t* WTq  = pos  + 196608;          // 512*512 bf16 each
    ushort_t* WTk  = WTq + 262144;
    ushort_t* WTv  = WTk + 262144;
    ushort_t* WTkr = WTv + 262144;

    hipMemsetAsync(vmean, 0, 1024 * sizeof(float), stream);

    wtrans_kernel<<<dim3(8, 8, 4), 256, 0, stream>>>(Wq, Wk, Wv, Wkr,
                                                     WTq, WTk, WTv, WTkr);
    pos_kernel<<<384, 256, 0, stream>>>(pos);
    qkv_gemm<<<dim3(32, 24), 256, 0, stream>>>(x, WTq, WTk, WTv, b_con, b_rel, bv,
                                               qcon, qrel, kbuf, vbuf);
    krel_gemm<<<dim3(3, 8), 256, 0, stream>>>(pos, WTkr, krel);
    rel_gemm<<<dim3(16, 8, 2), 256, 0, stream>>>(qrel, krel, R);
    vmean_kernel<<<dim3(2, 32), 512, 0, stream>>>(vbuf, vmean);
    attn_kernel<<<dim3(32, 8, 2), 256, 0, stream>>>(qcon, kbuf, vbuf, R, vmean,
                                                    xlen, out);
}